// Round 4
// baseline (740.089 us; speedup 1.0000x reference)
//
#include <hip/hip_runtime.h>
#include <hip/hip_bf16.h>

// Problem constants
#define B_   16
#define SEQ  577
#define P_   576      // SEQ-1 patches
#define DM   768
#define NH   12
#define DK   64
#define TEMP 8.0f     // sqrt(64)
#define LNEPS 1e-6f
#define EPS_  1e-12f
#define MROWS (B_*SEQ) // 9232

typedef __attribute__((ext_vector_type(8))) short short8;   // 8 bf16 (4 VGPRs)
typedef __attribute__((ext_vector_type(4))) float f32x4;    // MFMA C/D

// ---- ws layout (BYTE offsets; all 16B-aligned) ----
static const size_t PEN_B = 0;
static const size_t QH_B  = 21233664;
static const size_t KH_B  = 35414016;
static const size_t VH_B  = 49594368;
static const size_t VT_B  = 63774720;
static const size_t OBF_B = 79503360;
static const size_t WT_B  = 93683712;
static const size_t RN_B  = 98402304;
static const size_t FC_B  = QH_B;

// ---- dtype-adaptive loads: detect bf16 vs fp32 from ln_gamma bit pattern ----
__device__ __forceinline__ bool bf_flag(const void* gamma) {
    return (((const unsigned int*)gamma)[0] & 0xFFFFu) != 0u;
}
__device__ __forceinline__ float ldf(const void* p, size_t i, bool bf) {
    if (bf) {
        unsigned int w = ((unsigned int)((const unsigned short*)p)[i]) << 16;
        return __uint_as_float(w);
    }
    return ((const float*)p)[i];
}
__device__ __forceinline__ unsigned short f2bu(float x) {
    __hip_bfloat16 h = __float2bfloat16(x);
    return *(unsigned short*)&h;
}
// convert 8 consecutive fp32 (in LDS) to a bf16 short8 fragment
__device__ __forceinline__ short8 pack8(const float* p) {
    short8 r;
    #pragma unroll
    for (int u = 0; u < 8; u++) {
        __hip_bfloat16 h = __float2bfloat16(p[u]);
        r[u] = *(short*)&h;
    }
    return r;
}
// async global->LDS DMA, 16B per lane; LDS dest = wave-uniform base + lane*16
__device__ __forceinline__ void gload16(const void* g, void* l) {
    __builtin_amdgcn_global_load_lds(
        (const __attribute__((address_space(1))) unsigned int*)g,
        (__attribute__((address_space(3))) unsigned int*)l,
        16, 0, 0);
}

// ---- bijective XCD chunk swizzle (m204) ----
__device__ __forceinline__ int xcd_chunk(int orig, int nwg) {
    int q = nwg >> 3, r = nwg & 7;
    int xcd = orig & 7, slot = orig >> 3;
    int base = xcd < r ? xcd * (q + 1) : r * (q + 1) + (xcd - r) * q;
    return base + slot;
}

// ---------- row norms of patch embeddings (skip CLS row) ----------
__global__ __launch_bounds__(256) void k_rownorm(const void* __restrict__ emb,
                                                 const void* __restrict__ gamma,
                                                 float* __restrict__ rn) {
    bool bf = bf_flag(gamma);
    int row = blockIdx.x;
    int b = row / P_, i = row % P_;
    size_t base = ((size_t)(b * SEQ + 1 + i)) * DM;
    float s = 0.f;
    for (int c = threadIdx.x; c < DM; c += 256) { float v = ldf(emb, base + c, bf); s += v * v; }
    __shared__ float red[4];
    for (int off = 32; off > 0; off >>= 1) s += __shfl_down(s, off, 64);
    int lane = threadIdx.x & 63, w = threadIdx.x >> 6;
    if (lane == 0) red[w] = s;
    __syncthreads();
    if (threadIdx.x == 0) rn[row] = rsqrtf(red[0] + red[1] + red[2] + red[3] + EPS_);
}

// ---------- weight transpose+convert: W (k,n) fp32/bf16 -> WT (n,k) bf16 ----------
__global__ __launch_bounds__(256) void k_wt(const void* __restrict__ w0,
                                            const void* __restrict__ w1,
                                            const void* __restrict__ w2,
                                            const void* __restrict__ w3,
                                            const void* __restrict__ gamma,
                                            unsigned short* __restrict__ wt) {
    bool bf = bf_flag(gamma);
    int which = blockIdx.z;
    const void* W = which == 0 ? w0 : (which == 1 ? w1 : (which == 2 ? w2 : w3));
    unsigned short* WT = wt + (size_t)which * DM * DM;
    int k0 = blockIdx.y * 64, n0 = blockIdx.x * 64;
    __shared__ unsigned short Ts[64][69];
    int tid = threadIdx.x;
    {
        int kr = tid >> 2, nq = (tid & 3) * 16;
        size_t src = (size_t)(k0 + kr) * DM + n0 + nq;
        #pragma unroll
        for (int u = 0; u < 16; u++) Ts[kr][nq + u] = f2bu(ldf(W, src + u, bf));
    }
    __syncthreads();
    {
        int nr = tid >> 2, kq = (tid & 3) * 16;
        unsigned short tmp[16];
        #pragma unroll
        for (int u = 0; u < 16; u++) tmp[u] = Ts[kq + u][nr];
        uint4* dst = (uint4*)(WT + (size_t)(n0 + nr) * DM + k0 + kq);
        dst[0] = *(const uint4*)&tmp[0];
        dst[1] = *(const uint4*)&tmp[8];
    }
}

// ---------- penalty via MFMA + global_load_lds staging ----------
// 64x64 tile; A,B = emb rows (fp32: DMA raw fp32 into LDS, convert at frag read).
__global__ __launch_bounds__(256) void k_penalty_mfma(const void* __restrict__ emb,
                                                      const void* __restrict__ pos,
                                                      const void* __restrict__ gamma,
                                                      const float* __restrict__ rn,
                                                      float* __restrict__ pen) {
    bool bf = bf_flag(gamma);
    int p = xcd_chunk(blockIdx.x, 9 * 9 * B_);
    int b = p / 81; int rem = p % 81;
    int i0 = (rem / 9) * 64, j0 = (rem % 9) * 64;
    __shared__ __align__(16) float Af[64][64];   // 16 KB (fp32 mode) / bf16 aliased
    __shared__ __align__(16) float Bf[64][64];
    unsigned short (*Ab)[64] = (unsigned short(*)[64])Af;
    unsigned short (*Bb)[64] = (unsigned short(*)[64])Bf;
    int tid = threadIdx.x;
    int lane = tid & 63, w = tid >> 6;

    f32x4 acc[4];
    #pragma unroll
    for (int c = 0; c < 4; c++) acc[c] = (f32x4){0.f, 0.f, 0.f, 0.f};

    size_t ebase = ((size_t)b * SEQ + 1) * DM;   // skip CLS
    // staging pointers
    const float *aSf[4], *bSf[4]; void *aDf[4], *bDf[4];
    const unsigned short *aSb[2], *bSb[2]; void *aDb[2], *bDb[2];
    if (!bf) {
        #pragma unroll
        for (int s = 0; s < 4; s++) {
            int S = w * 4 + s;                       // 16 slots, 4 rows each
            int ra = i0 + S * 4 + (lane >> 4);
            int rb = j0 + S * 4 + (lane >> 4);
            aSf[s] = (const float*)emb + ebase + (size_t)ra * DM + (lane & 15) * 4;
            bSf[s] = (const float*)emb + ebase + (size_t)rb * DM + (lane & 15) * 4;
            aDf[s] = &Af[S * 4][0]; bDf[s] = &Bf[S * 4][0];
        }
    } else {
        #pragma unroll
        for (int s = 0; s < 2; s++) {
            int S = w * 2 + s;                       // 8 slots, 8 rows each
            int ra = i0 + S * 8 + (lane >> 3);
            int rb = j0 + S * 8 + (lane >> 3);
            aSb[s] = (const unsigned short*)emb + ebase + (size_t)ra * DM + (lane & 7) * 8;
            bSb[s] = (const unsigned short*)emb + ebase + (size_t)rb * DM + (lane & 7) * 8;
            aDb[s] = &Ab[S * 8][0]; bDb[s] = &Bb[S * 8][0];
        }
    }

    for (int kc = 0; kc < DM; kc += 64) {
        if (!bf) {
            #pragma unroll
            for (int s = 0; s < 4; s++) { gload16(aSf[s] + kc, aDf[s]); gload16(bSf[s] + kc, bDf[s]); }
        } else {
            #pragma unroll
            for (int s = 0; s < 2; s++) { gload16(aSb[s] + kc, aDb[s]); gload16(bSb[s] + kc, bDb[s]); }
        }
        __syncthreads();
        #pragma unroll
        for (int s = 0; s < 2; s++) {
            int co = s * 32 + (lane >> 4) * 8;
            short8 af = bf ? *(const short8*)&Ab[w * 16 + (lane & 15)][co]
                           : pack8(&Af[w * 16 + (lane & 15)][co]);
            #pragma unroll
            for (int c = 0; c < 4; c++) {
                short8 bfr = bf ? *(const short8*)&Bb[c * 16 + (lane & 15)][co]
                                : pack8(&Bf[c * 16 + (lane & 15)][co]);
                acc[c] = __builtin_amdgcn_mfma_f32_16x16x32_bf16(af, bfr, acc[c], 0, 0, 0);
            }
        }
        __syncthreads();
    }
    size_t pbase = (size_t)b * P_ * 2;
    int rbase = (lane >> 4) * 4, cbase = lane & 15;
    float pix[4], piy[4], rni_[4], pjx[4], pjy[4], rnj_[4];
    #pragma unroll
    for (int jj = 0; jj < 4; jj++) {
        int i = i0 + w * 16 + rbase + jj;
        pix[jj] = ldf(pos, pbase + (size_t)i * 2, bf);
        piy[jj] = ldf(pos, pbase + (size_t)i * 2 + 1, bf);
        rni_[jj] = rn[b * P_ + i];
    }
    #pragma unroll
    for (int c = 0; c < 4; c++) {
        int j = j0 + c * 16 + cbase;
        pjx[c] = ldf(pos, pbase + (size_t)j * 2, bf);
        pjy[c] = ldf(pos, pbase + (size_t)j * 2 + 1, bf);
        rnj_[c] = rn[b * P_ + j];
    }
    float* pp = pen + (size_t)b * P_ * P_;
    #pragma unroll
    for (int c = 0; c < 4; c++)
        #pragma unroll
        for (int jj = 0; jj < 4; jj++) {
            int i = i0 + w * 16 + rbase + jj;
            int j = j0 + c * 16 + cbase;
            float dx = pix[jj] - pjx[c], dy = piy[jj] - pjy[c];
            pp[(size_t)i * P_ + j] = acc[c][jj] * rni_[jj] * rnj_[c] * sqrtf(dx * dx + dy * dy + EPS_);
        }
}

// ---------- qkv projection via MFMA + global_load_lds staging ----------
// 128x128 tile, BK=64. A: raw fp32 DMA + convert-at-read (or bf16 direct).
__global__ __launch_bounds__(256) void k_proj_mfma(const void* __restrict__ q,
                                                   const void* __restrict__ k,
                                                   const void* __restrict__ v,
                                                   const unsigned short* __restrict__ wt,
                                                   const void* __restrict__ gamma,
                                                   unsigned short* __restrict__ qh,
                                                   unsigned short* __restrict__ kh,
                                                   unsigned short* __restrict__ vh) {
    bool bf = bf_flag(gamma);
    int p = xcd_chunk(blockIdx.x, 73 * 6 * 3);
    int which = p / (73 * 6);
    int rem = p % (73 * 6);
    int m0 = (rem / 6) * 128, n0 = (rem % 6) * 128;
    const void* X = which == 0 ? q : (which == 1 ? k : v);
    const unsigned short* WT = wt + (size_t)which * DM * DM;
    unsigned short* Y = which == 0 ? qh : (which == 1 ? kh : vh);
    float scale = which == 0 ? (1.0f / TEMP) : 1.0f;

    __shared__ __align__(16) float Af[128][64];            // 32 KB (fp32 A)
    __shared__ __align__(16) unsigned short Bs[128][64];   // 16 KB
    unsigned short (*Ab)[64] = (unsigned short(*)[64])Af;
    int tid = threadIdx.x;
    int lane = tid & 63, w = tid >> 6;
    int wr = w >> 1, wc = w & 1;

    f32x4 acc[4][4];
    #pragma unroll
    for (int r = 0; r < 4; r++)
        #pragma unroll
        for (int c = 0; c < 4; c++) acc[r][c] = (f32x4){0.f, 0.f, 0.f, 0.f};

    // staging pointers
    const float* aSf[8]; void* aDf[8];
    const unsigned short* aSb[4]; void* aDb[4];
    const unsigned short* bS[4]; void* bD[4];
    if (!bf) {
        #pragma unroll
        for (int s = 0; s < 8; s++) {
            int S = w * 8 + s;                       // 32 slots, 4 rows each
            int row = m0 + S * 4 + (lane >> 4); if (row >= MROWS) row = MROWS - 1;
            aSf[s] = (const float*)X + (size_t)row * DM + (lane & 15) * 4;
            aDf[s] = &Af[S * 4][0];
        }
    } else {
        #pragma unroll
        for (int s = 0; s < 4; s++) {
            int S = w * 4 + s;                       // 16 slots, 8 rows each
            int row = m0 + S * 8 + (lane >> 3); if (row >= MROWS) row = MROWS - 1;
            aSb[s] = (const unsigned short*)X + (size_t)row * DM + (lane & 7) * 8;
            aDb[s] = &Ab[S * 8][0];
        }
    }
    #pragma unroll
    for (int s = 0; s < 4; s++) {
        int S = w * 4 + s;
        int row = n0 + S * 8 + (lane >> 3);          // <= 767, in-bounds
        bS[s] = WT + (size_t)row * DM + (lane & 7) * 8;
        bD[s] = &Bs[S * 8][0];
    }

    for (int kc = 0; kc < DM; kc += 64) {
        if (!bf) {
            #pragma unroll
            for (int s = 0; s < 8; s++) gload16(aSf[s] + kc, aDf[s]);
        } else {
            #pragma unroll
            for (int s = 0; s < 4; s++) gload16(aSb[s] + kc, aDb[s]);
        }
        #pragma unroll
        for (int s = 0; s < 4; s++) gload16(bS[s] + kc, bD[s]);
        __syncthreads();
        #pragma unroll
        for (int s = 0; s < 2; s++) {
            int co = s * 32 + (lane >> 4) * 8;
            short8 af[4], bfr[4];
            #pragma unroll
            for (int r = 0; r < 4; r++) {
                int row = wr * 64 + r * 16 + (lane & 15);
                af[r] = bf ? *(const short8*)&Ab[row][co] : pack8(&Af[row][co]);
            }
            #pragma unroll
            for (int c = 0; c < 4; c++)
                bfr[c] = *(const short8*)&Bs[wc * 64 + c * 16 + (lane & 15)][co];
            #pragma unroll
            for (int r = 0; r < 4; r++)
                #pragma unroll
                for (int c = 0; c < 4; c++)
                    acc[r][c] = __builtin_amdgcn_mfma_f32_16x16x32_bf16(af[r], bfr[c], acc[r][c], 0, 0, 0);
        }
        __syncthreads();
    }
    int rbase = (lane >> 4) * 4, cbase = lane & 15;
    #pragma unroll
    for (int r = 0; r < 4; r++) {
        #pragma unroll
        for (int jj = 0; jj < 4; jj++) {
            int gm = m0 + wr * 64 + r * 16 + rbase + jj;
            if (gm < MROWS) {
                int b = gm / SEQ, n = gm % SEQ;
                #pragma unroll
                for (int c = 0; c < 4; c++) {
                    int gc = n0 + wc * 64 + c * 16 + cbase;
                    int h = gc >> 6, d = gc & 63;
                    Y[(((size_t)(b * NH + h) * SEQ) + n) * DK + d] = f2bu(acc[r][c][jj] * scale);
                }
            }
        }
    }
}

// ---------- V transpose: vh (B,H,N,64) -> vt (B,H,64,640) ----------
__global__ __launch_bounds__(256) void k_vt(const unsigned short* __restrict__ vh,
                                            unsigned short* __restrict__ vt) {
    int ntile = blockIdx.x;       // 0..9
    int bh = blockIdx.y;          // 0..191
    __shared__ unsigned short Ts[64][72];
    int tid = threadIdx.x;
    int n0 = ntile * 64;
    {
        int r = tid >> 2, c = (tid & 3) * 16;
        int gn = n0 + r; if (gn > 576) gn = 576;
        const uint4* src = (const uint4*)(vh + ((size_t)bh * SEQ + gn) * DK + c);
        uint4 a = src[0], bv = src[1];
        *(uint4*)&Ts[r][c] = a; *(uint4*)&Ts[r][c + 8] = bv;
    }
    __syncthreads();
    {
        int d = tid >> 2, c = (tid & 3) * 16;
        unsigned short tmp[16];
        #pragma unroll
        for (int u = 0; u < 16; u++) tmp[u] = Ts[c + u][d];
        uint4* dst = (uint4*)(vt + ((size_t)bh * DK + d) * 640 + n0 + c);
        dst[0] = *(uint4*)&tmp[0];
        dst[1] = *(uint4*)&tmp[8];
    }
}

// ---------- flash attention: 512 threads, QBLK=128, 8 waves of 16-row strips ----------
__global__ __launch_bounds__(512, 4) void k_attn2(const unsigned short* __restrict__ qh,
                                                  const unsigned short* __restrict__ kh,
                                                  const unsigned short* __restrict__ vt,
                                                  const float* __restrict__ pen,
                                                  unsigned short* __restrict__ O) {
    const int NWG = 5 * NH * B_;               // 960
    int flat = blockIdx.x + 5 * (blockIdx.y + NH * blockIdx.z);
    int id = (flat & 7) * (NWG >> 3) + (flat >> 3);
    int it = id % 5; int t2 = id / 5;
    int h = t2 % NH;  int b = t2 / NH;
    int bh = b * NH + h;
    int i0 = it * 128;

    __shared__ __align__(16) unsigned short Qs[128][72];
    __shared__ __align__(16) unsigned short Ks[64][72];
    __shared__ __align__(16) unsigned short Vs[64][72];
    __shared__ __align__(16) unsigned short Ps[128][72];
    int tid = threadIdx.x;
    int lane = tid & 63, w = tid >> 6;          // 8 waves

    {
        int r = tid >> 2, c = (tid & 3) * 16;
        int gi = i0 + r; if (gi > 576) gi = 576;
        const uint4* src = (const uint4*)(qh + ((size_t)bh * SEQ + gi) * DK + c);
        uint4 a = src[0], bv = src[1];
        *(uint4*)&Qs[r][c] = a; *(uint4*)&Qs[r][c + 8] = bv;
    }
    __syncthreads();
    short8 qfrag[2];
    #pragma unroll
    for (int s = 0; s < 2; s++)
        qfrag[s] = *(const short8*)&Qs[w * 16 + (lane & 15)][s * 32 + (lane >> 4) * 8];

    f32x4 o_acc[4];
    #pragma unroll
    for (int i = 0; i < 4; i++) o_acc[i] = (f32x4){0.f, 0.f, 0.f, 0.f};
    float m_run[4], l_run[4];
    #pragma unroll
    for (int r = 0; r < 4; r++) { m_run[r] = -1e30f; l_run[r] = 0.f; }

    const float* penb = pen + (size_t)b * P_ * P_;
    int colbase = lane & 15;
    int rloc = (lane >> 4) * 4;

    const float* prow[4]; bool iok[4];
    #pragma unroll
    for (int rg = 0; rg < 4; rg++) {
        int i = i0 + w * 16 + rloc + rg;
        int ii = i < 1 ? 1 : (i > 576 ? 576 : i);
        prow[rg] = penb + (size_t)(ii - 1) * P_;
        iok[rg] = (i >= 1 && i <= 576);
    }

    for (int kt = 0; kt < 10; kt++) {
        int j0 = kt * 64;
        {
            int r = tid >> 3, c = (tid & 7) * 8;
            int gj = j0 + r; if (gj > 576) gj = 576;
            *(uint4*)&Ks[r][c] = *(const uint4*)(kh + ((size_t)bh * SEQ + gj) * DK + c);
            *(uint4*)&Vs[r][c] = *(const uint4*)(vt + ((size_t)bh * DK + r) * 640 + j0 + c);
        }
        __syncthreads();

        float pf[4][4];
        #pragma unroll
        for (int rg = 0; rg < 4; rg++) {
            #pragma unroll
            for (int nt = 0; nt < 4; nt++) {
                int j = j0 + nt * 16 + colbase;
                int jj = j < 1 ? 1 : (j > 576 ? 576 : j);
                float pv = prow[rg][jj - 1];
                pf[rg][nt] = (iok[rg] && j >= 1 && j <= 576) ? pv : 0.f;
            }
        }

        f32x4 sfrag[4];
        __builtin_amdgcn_s_setprio(1);
        #pragma unroll
        for (int nt = 0; nt < 4; nt++) {
            f32x4 acc = (f32x4){0.f, 0.f, 0.f, 0.f};
            #pragma unroll
            for (int s = 0; s < 2; s++) {
                short8 bfrag = *(const short8*)&Ks[nt * 16 + colbase][s * 32 + (lane >> 4) * 8];
                acc = __builtin_amdgcn_mfma_f32_16x16x32_bf16(qfrag[s], bfrag, acc, 0, 0, 0);
            }
            sfrag[nt] = acc;
        }
        __builtin_amdgcn_s_setprio(0);

        #pragma unroll
        for (int nt = 0; nt < 4; nt++) {
            int j = j0 + nt * 16 + colbase;
            #pragma unroll
            for (int rg = 0; rg < 4; rg++) {
                float sv = sfrag[nt][rg] - pf[rg][nt];
                if (j > 576) sv = -1e30f;
                sfrag[nt][rg] = sv;
            }
        }
        float alpha[4];
        #pragma unroll
        for (int rg = 0; rg < 4; rg++) {
            float t = fmaxf(fmaxf(sfrag[0][rg], sfrag[1][rg]),
                            fmaxf(sfrag[2][rg], sfrag[3][rg]));
            #pragma unroll
            for (int off = 1; off < 16; off <<= 1) t = fmaxf(t, __shfl_xor(t, off, 64));
            float mn = fmaxf(m_run[rg], t);
            alpha[rg] = __expf(m_run[rg] - mn);
            m_run[rg] = mn;
        }
        float rsum[4] = {0.f, 0.f, 0.f, 0.f};
        #pragma unroll
        for (int nt = 0; nt < 4; nt++) {
            #pragma unroll
            for (int rg = 0; rg < 4; rg++) {
                float p = __expf(sfrag[nt][rg] - m_run[rg]);
                rsum[rg] += p;
                Ps[w * 16 + rloc + rg][nt * 16 + colbase] = f2bu(p);
            }
        }
        #pragma unroll
        for (int rg = 0; rg < 4; rg++) {
            float t = rsum[rg];
            #pragma unroll
            for (int off = 1; off < 16; off <<= 1) t += __shfl_xor(t, off, 64);
            l_run[rg] = l_run[rg] * alpha[rg] + t;
        }
        #pragma unroll
        for (int nt = 0; nt < 4; nt++)
            #pragma unroll
            for (int rg = 0; rg < 4; rg++) o_acc[nt][rg] *= alpha[rg];

        __builtin_amdgcn_s_setprio(1);
        #pragma unroll
        for (int s = 0; s < 2; s++) {
            short8 afrag = *(const short8*)&Ps[w * 16 + (lane & 15)][s * 32 + (lane >> 4) * 8];
            #pragma unroll
            for (int nt = 0; nt < 4; nt++) {
                short8 bfrag = *(const short8*)&Vs[nt * 16 + colbase][s * 32 + (lane >> 4) * 8];
                o_acc[nt] = __builtin_amdgcn_mfma_f32_16x16x32_bf16(afrag, bfrag, o_acc[nt], 0, 0, 0);
            }
        }
        __builtin_amdgcn_s_setprio(0);
        __syncthreads();
    }
    #pragma unroll
    for (int rg = 0; rg < 4; rg++) {
        int i = i0 + w * 16 + rloc + rg;
        if (i < SEQ) {
            float linv = 1.0f / l_run[rg];
            #pragma unroll
            for (int nt = 0; nt < 4; nt++) {
                int d = nt * 16 + colbase;
                O[(((size_t)(b * SEQ + i)) * NH + h) * DK + d] = f2bu(o_acc[nt][rg] * linv);
            }
        }
    }
}

// ---------- out projection via MFMA + global_load_lds (both operands bf16) ----------
__global__ __launch_bounds__(256) void k_fc_mfma(const unsigned short* __restrict__ Obf,
                                                 const unsigned short* __restrict__ wtfc,
                                                 const void* __restrict__ qin,
                                                 const void* __restrict__ gamma,
                                                 float* __restrict__ fcout) {
    bool bf = bf_flag(gamma);
    int p = xcd_chunk(blockIdx.x, 73 * 6);
    int m0 = (p / 6) * 128, n0 = (p % 6) * 128;
    __shared__ __align__(16) unsigned short As[128][64];
    __shared__ __align__(16) unsigned short Bs[128][64];
    int tid = threadIdx.x;
    int lane = tid & 63, w = tid >> 6;
    int wr = w >> 1, wc = w & 1;

    f32x4 acc[4][4];
    #pragma unroll
    for (int r = 0; r < 4; r++)
        #pragma unroll
        for (int c = 0; c < 4; c++) acc[r][c] = (f32x4){0.f, 0.f, 0.f, 0.f};

    const unsigned short *aS[4], *bS[4]; void *aD[4], *bD[4];
    #pragma unroll
    for (int s = 0; s < 4; s++) {
        int S = w * 4 + s;
        int ra = m0 + S * 8 + (lane >> 3); if (ra >= MROWS) ra = MROWS - 1;
        int rb = n0 + S * 8 + (lane >> 3);
        aS[s] = Obf + (size_t)ra * DM + (lane & 7) * 8;
        bS[s] = wtfc + (size_t)rb * DM + (lane & 7) * 8;
        aD[s] = &As[S * 8][0]; bD[s] = &Bs[S * 8][0];
    }

    for (int kc = 0; kc < DM; kc += 64) {
        #pragma unroll
        for (int s = 0; s < 4; s++) { gload16(aS[s] + kc, aD[s]); gload16(bS[s] + kc, bD[s]); }
        __syncthreads();
        #pragma unroll
        for (int s = 0; s < 2; s++) {
            int co = s * 32 + (lane >> 4) * 8;
            short8 af[4], bfr[4];
            #pragma unroll
            for (int r = 0; r < 4; r++)
                af[r] = *(const short8*)&As[wr * 64 + r * 16 + (lane & 15)][co];
            #pragma unroll
            for (int c = 0; c < 4; c++)
                bfr[c] = *(const short8*)&Bs[wc * 64 + c * 16 + (lane & 15)][co];
            #pragma unroll
            for (int r = 0; r < 4; r++)
                #pragma unroll
                for (int c = 0; c < 4; c++)
                    acc[r][c] = __builtin_amdgcn_mfma_f32_16x16x32_bf16(af[r], bfr[c], acc[r][c], 0, 0, 0);
        }
        __syncthreads();
    }
    int rbase = (lane >> 4) * 4, cbase = lane & 15;
    #pragma unroll
    for (int r = 0; r < 4; r++) {
        #pragma unroll
        for (int jj = 0; jj < 4; jj++) {
            int gm = m0 + wr * 64 + r * 16 + rbase + jj;
            if (gm < MROWS) {
                #pragma unroll
                for (int c = 0; c < 4; c++) {
                    int gc = n0 + wc * 64 + c * 16 + cbase;
                    fcout[(size_t)gm * DM + gc] = acc[r][c][jj] + ldf(qin, (size_t)gm * DM + gc, bf);
                }
            }
        }
    }
}

// ---------- layernorm (dtype-adaptive output) ----------
__global__ __launch_bounds__(256) void k_ln(const float* __restrict__ x,
                                            const void* __restrict__ gamma,
                                            const void* __restrict__ beta,
                                            void* __restrict__ out) {
    bool bf = bf_flag(gamma);
    int row = blockIdx.x;
    const float* xr = x + (size_t)row * DM;
    int tid = threadIdx.x;
    float v[3];
    float ssum = 0.f;
    #pragma unroll
    for (int u = 0; u < 3; u++) { v[u] = xr[tid + u * 256]; ssum += v[u]; }
    __shared__ float red[4];
    __shared__ float mu_s, var_s;
    float t = ssum;
    for (int off = 32; off > 0; off >>= 1) t += __shfl_down(t, off, 64);
    int lane = tid & 63, w = tid >> 6;
    if (lane == 0) red[w] = t;
    __syncthreads();
    if (tid == 0) mu_s = (red[0] + red[1] + red[2] + red[3]) * (1.0f / DM);
    __syncthreads();
    float mu = mu_s;
    float vs = 0.f;
    #pragma unroll
    for (int u = 0; u < 3; u++) { float d = v[u] - mu; vs += d * d; }
    t = vs;
    for (int off = 32; off > 0; off >>= 1) t += __shfl_down(t, off, 64);
    if (lane == 0) red[w] = t;
    __syncthreads();
    if (tid == 0) var_s = (red[0] + red[1] + red[2] + red[3]) * (1.0f / DM);
    __syncthreads();
    float rstd = rsqrtf(var_s + LNEPS);
    #pragma unroll
    for (int u = 0; u < 3; u++) {
        int c = tid + u * 256;
        float val = (v[u] - mu) * rstd * ldf(gamma, c, bf) + ldf(beta, c, bf);
        size_t idx = (size_t)row * DM + c;
        if (bf) ((__hip_bfloat16*)out)[idx] = __float2bfloat16(val);
        else    ((float*)out)[idx] = val;
    }
}

extern "C" void kernel_launch(void* const* d_in, const int* in_sizes, int n_in,
                              void* d_out, int out_size, void* d_ws, size_t ws_size,
                              hipStream_t stream) {
    const void* q   = d_in[0];
    const void* k   = d_in[1];
    const void* v   = d_in[2];
    const void* pos = d_in[3];
    const void* pe  = d_in[4];
    const void* wq  = d_in[5];
    const void* wk  = d_in[6];
    const void* wv  = d_in[7];
    const void* wfc = d_in[8];
    const void* gam = d_in[9];
    const void* bet = d_in[10];
    char* wsb = (char*)d_ws;
    float*          pen = (float*)(wsb + PEN_B);
    unsigned short* qh  = (unsigned short*)(wsb + QH_B);
    unsigned short* kh  = (unsigned short*)(wsb + KH_B);
    unsigned short* vh  = (unsigned short*)(wsb + VH_B);
    unsigned short* vt  = (unsigned short*)(wsb + VT_B);
    unsigned short* Obf = (unsigned short*)(wsb + OBF_B);
    unsigned short* wt  = (unsigned short*)(wsb + WT_B);
    float*          rn  = (float*)(wsb + RN_B);
    float*          fc  = (float*)(wsb + FC_B);

    k_wt<<<dim3(12, 12, 4), 256, 0, stream>>>(wq, wk, wv, wfc, gam, wt);
    k_rownorm<<<B_ * P_, 256, 0, stream>>>(pe, gam, rn);
    k_penalty_mfma<<<dim3(9 * 9 * B_), 256, 0, stream>>>(pe, pos, gam, rn, pen);
    k_proj_mfma<<<dim3(73 * 6 * 3), 256, 0, stream>>>(q, k, v, wt, gam, qh, kh, vh);
    k_vt<<<dim3(10, 192), 256, 0, stream>>>(vh, vt);
    k_attn2<<<dim3(5, NH, B_), 512, 0, stream>>>(qh, kh, vt, pen, Obf);
    k_fc_mfma<<<dim3(73 * 6), 256, 0, stream>>>(Obf, wt + (size_t)3 * DM * DM, q, gam, fc);
    k_ln<<<MROWS, 256, 0, stream>>>(fc, gam, bet, d_out);
}

// Round 5
// 393.321 us; speedup vs baseline: 1.8816x; 1.8816x over previous
//
#include <hip/hip_runtime.h>
#include <hip/hip_bf16.h>

// Problem constants
#define B_   16
#define SEQ  577
#define P_   576      // SEQ-1 patches
#define DM   768
#define NH   12
#define DK   64
#define TEMP 8.0f     // sqrt(64)
#define LNEPS 1e-6f
#define EPS_  1e-12f
#define MROWS (B_*SEQ) // 9232

typedef __attribute__((ext_vector_type(8))) short short8;   // 8 bf16 (4 VGPRs)
typedef __attribute__((ext_vector_type(4))) float f32x4;    // MFMA C/D

// ---- ws layout (BYTE offsets; all 16B-aligned) ----
static const size_t PEN_B = 0;
static const size_t QH_B  = 21233664;
static const size_t KH_B  = 35414016;
static const size_t VH_B  = 49594368;
static const size_t VT_B  = 63774720;
static const size_t OBF_B = 79503360;
static const size_t WT_B  = 93683712;
static const size_t RN_B  = 98402304;
static const size_t FC_B  = QH_B;

// ---- dtype-adaptive loads: detect bf16 vs fp32 from ln_gamma bit pattern ----
__device__ __forceinline__ bool bf_flag(const void* gamma) {
    return (((const unsigned int*)gamma)[0] & 0xFFFFu) != 0u;
}
__device__ __forceinline__ float ldf(const void* p, size_t i, bool bf) {
    if (bf) {
        unsigned int w = ((unsigned int)((const unsigned short*)p)[i]) << 16;
        return __uint_as_float(w);
    }
    return ((const float*)p)[i];
}
__device__ __forceinline__ unsigned short f2bu(float x) {
    __hip_bfloat16 h = __float2bfloat16(x);
    return *(unsigned short*)&h;
}
// convert two float4 granules to one bf16 short8 fragment
__device__ __forceinline__ short8 cvt8(float4 lo, float4 hi) {
    short8 r;
    r[0] = (short)f2bu(lo.x); r[1] = (short)f2bu(lo.y);
    r[2] = (short)f2bu(lo.z); r[3] = (short)f2bu(lo.w);
    r[4] = (short)f2bu(hi.x); r[5] = (short)f2bu(hi.y);
    r[6] = (short)f2bu(hi.z); r[7] = (short)f2bu(hi.w);
    return r;
}
// async global->LDS DMA, 16B per lane; LDS dest = wave-uniform base + lane*16
__device__ __forceinline__ void gload16(const void* g, void* l) {
    __builtin_amdgcn_global_load_lds(
        (const __attribute__((address_space(1))) unsigned int*)g,
        (__attribute__((address_space(3))) unsigned int*)l,
        16, 0, 0);
}

// ---- bijective XCD chunk swizzle (m204) ----
__device__ __forceinline__ int xcd_chunk(int orig, int nwg) {
    int q = nwg >> 3, r = nwg & 7;
    int xcd = orig & 7, slot = orig >> 3;
    int base = xcd < r ? xcd * (q + 1) : r * (q + 1) + (xcd - r) * q;
    return base + slot;
}

// ---------- row norms of patch embeddings (skip CLS row) ----------
__global__ __launch_bounds__(256) void k_rownorm(const void* __restrict__ emb,
                                                 const void* __restrict__ gamma,
                                                 float* __restrict__ rn) {
    bool bf = bf_flag(gamma);
    int row = blockIdx.x;
    int b = row / P_, i = row % P_;
    size_t base = ((size_t)(b * SEQ + 1 + i)) * DM;
    float s = 0.f;
    for (int c = threadIdx.x; c < DM; c += 256) { float v = ldf(emb, base + c, bf); s += v * v; }
    __shared__ float red[4];
    for (int off = 32; off > 0; off >>= 1) s += __shfl_down(s, off, 64);
    int lane = threadIdx.x & 63, w = threadIdx.x >> 6;
    if (lane == 0) red[w] = s;
    __syncthreads();
    if (threadIdx.x == 0) rn[row] = rsqrtf(red[0] + red[1] + red[2] + red[3] + EPS_);
}

// ---------- weight transpose+convert: W (k,n) fp32/bf16 -> WT (n,k) bf16 ----------
__global__ __launch_bounds__(256) void k_wt(const void* __restrict__ w0,
                                            const void* __restrict__ w1,
                                            const void* __restrict__ w2,
                                            const void* __restrict__ w3,
                                            const void* __restrict__ gamma,
                                            unsigned short* __restrict__ wt) {
    bool bf = bf_flag(gamma);
    int which = blockIdx.z;
    const void* W = which == 0 ? w0 : (which == 1 ? w1 : (which == 2 ? w2 : w3));
    unsigned short* WT = wt + (size_t)which * DM * DM;
    int k0 = blockIdx.y * 64, n0 = blockIdx.x * 64;
    __shared__ unsigned short Ts[64][69];
    int tid = threadIdx.x;
    {
        int kr = tid >> 2, nq = (tid & 3) * 16;
        size_t src = (size_t)(k0 + kr) * DM + n0 + nq;
        #pragma unroll
        for (int u = 0; u < 16; u++) Ts[kr][nq + u] = f2bu(ldf(W, src + u, bf));
    }
    __syncthreads();
    {
        int nr = tid >> 2, kq = (tid & 3) * 16;
        unsigned short tmp[16];
        #pragma unroll
        for (int u = 0; u < 16; u++) tmp[u] = Ts[kq + u][nr];
        uint4* dst = (uint4*)(WT + (size_t)(n0 + nr) * DM + k0 + kq);
        dst[0] = *(const uint4*)&tmp[0];
        dst[1] = *(const uint4*)&tmp[8];
    }
}

// ---------- penalty via MFMA + gload_lds + T2 granule swizzle ----------
// 64x64 tile; LDS dest linear, source pre-swizzled (granule ^= row&7), read swizzled.
__global__ __launch_bounds__(256) void k_penalty_mfma(const void* __restrict__ emb,
                                                      const void* __restrict__ pos,
                                                      const void* __restrict__ gamma,
                                                      const float* __restrict__ rn,
                                                      float* __restrict__ pen) {
    bool bf = bf_flag(gamma);
    int p = xcd_chunk(blockIdx.x, 9 * 9 * B_);
    int b = p / 81; int rem = p % 81;
    int i0 = (rem / 9) * 64, j0 = (rem % 9) * 64;
    __shared__ __align__(16) float Af[64][64];   // fp32 mode; bf16 aliases low half
    __shared__ __align__(16) float Bf[64][64];
    unsigned short (*Ab)[64] = (unsigned short(*)[64])Af;
    unsigned short (*Bb)[64] = (unsigned short(*)[64])Bf;
    int tid = threadIdx.x;
    int lane = tid & 63, w = tid >> 6;
    int r3 = lane & 7;

    f32x4 acc[4];
    #pragma unroll
    for (int c = 0; c < 4; c++) acc[c] = (f32x4){0.f, 0.f, 0.f, 0.f};

    size_t ebase = ((size_t)b * SEQ + 1) * DM;   // skip CLS
    const float *aSf[4], *bSf[4]; void *aDf[4], *bDf[4];
    const unsigned short *aSb[2], *bSb[2]; void *aDb[2], *bDb[2];
    if (!bf) {
        #pragma unroll
        for (int s = 0; s < 4; s++) {
            int S = w * 4 + s;                       // 16 slots, 4 rows each
            int rl = S * 4 + (lane >> 4);            // tile-local row
            int gsw = (lane & 15) ^ (rl & 7);        // pre-swizzled source granule
            aSf[s] = (const float*)emb + ebase + (size_t)(i0 + rl) * DM + (gsw << 2);
            bSf[s] = (const float*)emb + ebase + (size_t)(j0 + rl) * DM + (gsw << 2);
            aDf[s] = &Af[S * 4][0]; bDf[s] = &Bf[S * 4][0];
        }
    } else {
        #pragma unroll
        for (int s = 0; s < 2; s++) {
            int S = w * 2 + s;                       // 8 slots, 8 rows each
            int rl = S * 8 + (lane >> 3);
            int gsw = (lane & 7) ^ (lane >> 3);      // rl&7 == lane>>3
            aSb[s] = (const unsigned short*)emb + ebase + (size_t)(i0 + rl) * DM + (gsw << 3);
            bSb[s] = (const unsigned short*)emb + ebase + (size_t)(j0 + rl) * DM + (gsw << 3);
            aDb[s] = &Ab[S * 8][0]; bDb[s] = &Bb[S * 8][0];
        }
    }

    for (int kc = 0; kc < DM; kc += 64) {
        if (!bf) {
            #pragma unroll
            for (int s = 0; s < 4; s++) { gload16(aSf[s] + kc, aDf[s]); gload16(bSf[s] + kc, bDf[s]); }
        } else {
            #pragma unroll
            for (int s = 0; s < 2; s++) { gload16(aSb[s] + kc, aDb[s]); gload16(bSb[s] + kc, bDb[s]); }
        }
        __syncthreads();
        #pragma unroll
        for (int s = 0; s < 2; s++) {
            short8 af, bfr[4];
            if (bf) {
                int g = (s * 4 + (lane >> 4)) ^ r3;
                af = *(const short8*)((const char*)&Ab[w * 16 + (lane & 15)][0] + (g << 4));
                #pragma unroll
                for (int c = 0; c < 4; c++)
                    bfr[c] = *(const short8*)((const char*)&Bb[c * 16 + (lane & 15)][0] + (g << 4));
            } else {
                int g0 = s * 8 + (lane >> 4) * 2;
                const float* ra = &Af[w * 16 + (lane & 15)][0];
                af = cvt8(*(const float4*)(ra + ((g0 ^ r3) << 2)),
                          *(const float4*)(ra + (((g0 + 1) ^ r3) << 2)));
                #pragma unroll
                for (int c = 0; c < 4; c++) {
                    const float* rb = &Bf[c * 16 + (lane & 15)][0];
                    bfr[c] = cvt8(*(const float4*)(rb + ((g0 ^ r3) << 2)),
                                  *(const float4*)(rb + (((g0 + 1) ^ r3) << 2)));
                }
            }
            #pragma unroll
            for (int c = 0; c < 4; c++)
                acc[c] = __builtin_amdgcn_mfma_f32_16x16x32_bf16(af, bfr[c], acc[c], 0, 0, 0);
        }
        __syncthreads();
    }
    size_t pbase = (size_t)b * P_ * 2;
    int rbase = (lane >> 4) * 4, cbase = lane & 15;
    float pix[4], piy[4], rni_[4], pjx[4], pjy[4], rnj_[4];
    #pragma unroll
    for (int jj = 0; jj < 4; jj++) {
        int i = i0 + w * 16 + rbase + jj;
        pix[jj] = ldf(pos, pbase + (size_t)i * 2, bf);
        piy[jj] = ldf(pos, pbase + (size_t)i * 2 + 1, bf);
        rni_[jj] = rn[b * P_ + i];
    }
    #pragma unroll
    for (int c = 0; c < 4; c++) {
        int j = j0 + c * 16 + cbase;
        pjx[c] = ldf(pos, pbase + (size_t)j * 2, bf);
        pjy[c] = ldf(pos, pbase + (size_t)j * 2 + 1, bf);
        rnj_[c] = rn[b * P_ + j];
    }
    float* pp = pen + (size_t)b * P_ * P_;
    #pragma unroll
    for (int c = 0; c < 4; c++)
        #pragma unroll
        for (int jj = 0; jj < 4; jj++) {
            int i = i0 + w * 16 + rbase + jj;
            int j = j0 + c * 16 + cbase;
            float dx = pix[jj] - pjx[c], dy = piy[jj] - pjy[c];
            pp[(size_t)i * P_ + j] = acc[c][jj] * rni_[jj] * rnj_[c] * sqrtf(dx * dx + dy * dy + EPS_);
        }
}

// ---------- qkv projection via MFMA + gload_lds + T2 granule swizzle ----------
__global__ __launch_bounds__(256) void k_proj_mfma(const void* __restrict__ q,
                                                   const void* __restrict__ k,
                                                   const void* __restrict__ v,
                                                   const unsigned short* __restrict__ wt,
                                                   const void* __restrict__ gamma,
                                                   unsigned short* __restrict__ qh,
                                                   unsigned short* __restrict__ kh,
                                                   unsigned short* __restrict__ vh) {
    bool bf = bf_flag(gamma);
    int p = xcd_chunk(blockIdx.x, 73 * 6 * 3);
    int which = p / (73 * 6);
    int rem = p % (73 * 6);
    int m0 = (rem / 6) * 128, n0 = (rem % 6) * 128;
    const void* X = which == 0 ? q : (which == 1 ? k : v);
    const unsigned short* WT = wt + (size_t)which * DM * DM;
    unsigned short* Y = which == 0 ? qh : (which == 1 ? kh : vh);
    float scale = which == 0 ? (1.0f / TEMP) : 1.0f;

    __shared__ __align__(16) float Af[128][64];            // fp32 A; bf16 aliases half
    __shared__ __align__(16) unsigned short Bs2[128][64];
    unsigned short (*Ab)[64] = (unsigned short(*)[64])Af;
    int tid = threadIdx.x;
    int lane = tid & 63, w = tid >> 6;
    int wr = w >> 1, wc = w & 1;
    int r3 = lane & 7;

    f32x4 acc[4][4];
    #pragma unroll
    for (int r = 0; r < 4; r++)
        #pragma unroll
        for (int c = 0; c < 4; c++) acc[r][c] = (f32x4){0.f, 0.f, 0.f, 0.f};

    const float* aSf[8]; void* aDf[8];
    const unsigned short* aSb[4]; void* aDb[4];
    const unsigned short* bS[4]; void* bD[4];
    if (!bf) {
        #pragma unroll
        for (int s = 0; s < 8; s++) {
            int S = w * 8 + s;                       // 32 slots, 4 rows each
            int rl = S * 4 + (lane >> 4);
            int row = m0 + rl; if (row >= MROWS) row = MROWS - 1;
            int gsw = (lane & 15) ^ (rl & 7);
            aSf[s] = (const float*)X + (size_t)row * DM + (gsw << 2);
            aDf[s] = &Af[S * 4][0];
        }
    } else {
        #pragma unroll
        for (int s = 0; s < 4; s++) {
            int S = w * 4 + s;                       // 16 slots, 8 rows each
            int rl = S * 8 + (lane >> 3);
            int row = m0 + rl; if (row >= MROWS) row = MROWS - 1;
            int gsw = (lane & 7) ^ (lane >> 3);
            aSb[s] = (const unsigned short*)X + (size_t)row * DM + (gsw << 3);
            aDb[s] = &Ab[S * 8][0];
        }
    }
    #pragma unroll
    for (int s = 0; s < 4; s++) {
        int S = w * 4 + s;
        int rl = S * 8 + (lane >> 3);
        int gsw = (lane & 7) ^ (lane >> 3);
        bS[s] = WT + (size_t)(n0 + rl) * DM + (gsw << 3);
        bD[s] = &Bs2[S * 8][0];
    }

    for (int kc = 0; kc < DM; kc += 64) {
        if (!bf) {
            #pragma unroll
            for (int s = 0; s < 8; s++) gload16(aSf[s] + kc, aDf[s]);
        } else {
            #pragma unroll
            for (int s = 0; s < 4; s++) gload16(aSb[s] + kc, aDb[s]);
        }
        #pragma unroll
        for (int s = 0; s < 4; s++) gload16(bS[s] + kc, bD[s]);
        __syncthreads();
        #pragma unroll
        for (int s = 0; s < 2; s++) {
            short8 af[4], bfr[4];
            int g16 = (s * 4 + (lane >> 4)) ^ r3;    // bf16 granule
            int g0 = s * 8 + (lane >> 4) * 2;        // fp32 granules
            #pragma unroll
            for (int r = 0; r < 4; r++) {
                int row = wr * 64 + r * 16 + (lane & 15);
                if (bf) {
                    af[r] = *(const short8*)((const char*)&Ab[row][0] + (g16 << 4));
                } else {
                    const float* ra = &Af[row][0];
                    af[r] = cvt8(*(const float4*)(ra + ((g0 ^ r3) << 2)),
                                 *(const float4*)(ra + (((g0 + 1) ^ r3) << 2)));
                }
            }
            #pragma unroll
            for (int c = 0; c < 4; c++)
                bfr[c] = *(const short8*)((const char*)&Bs2[wc * 64 + c * 16 + (lane & 15)][0] + (g16 << 4));
            #pragma unroll
            for (int r = 0; r < 4; r++)
                #pragma unroll
                for (int c = 0; c < 4; c++)
                    acc[r][c] = __builtin_amdgcn_mfma_f32_16x16x32_bf16(af[r], bfr[c], acc[r][c], 0, 0, 0);
        }
        __syncthreads();
    }
    int rbase = (lane >> 4) * 4, cbase = lane & 15;
    #pragma unroll
    for (int r = 0; r < 4; r++) {
        #pragma unroll
        for (int jj = 0; jj < 4; jj++) {
            int gm = m0 + wr * 64 + r * 16 + rbase + jj;
            if (gm < MROWS) {
                int b = gm / SEQ, n = gm % SEQ;
                #pragma unroll
                for (int c = 0; c < 4; c++) {
                    int gc = n0 + wc * 64 + c * 16 + cbase;
                    int h = gc >> 6, d = gc & 63;
                    Y[(((size_t)(b * NH + h) * SEQ) + n) * DK + d] = f2bu(acc[r][c][jj] * scale);
                }
            }
        }
    }
}

// ---------- V transpose: vh (B,H,N,64) -> vt (B,H,64,640) ----------
__global__ __launch_bounds__(256) void k_vt(const unsigned short* __restrict__ vh,
                                            unsigned short* __restrict__ vt) {
    int ntile = blockIdx.x;       // 0..9
    int bh = blockIdx.y;          // 0..191
    __shared__ unsigned short Ts[64][72];
    int tid = threadIdx.x;
    int n0 = ntile * 64;
    {
        int r = tid >> 2, c = (tid & 3) * 16;
        int gn = n0 + r; if (gn > 576) gn = 576;
        const uint4* src = (const uint4*)(vh + ((size_t)bh * SEQ + gn) * DK + c);
        uint4 a = src[0], bv = src[1];
        *(uint4*)&Ts[r][c] = a; *(uint4*)&Ts[r][c + 8] = bv;
    }
    __syncthreads();
    {
        int d = tid >> 2, c = (tid & 3) * 16;
        unsigned short tmp[16];
        #pragma unroll
        for (int u = 0; u < 16; u++) tmp[u] = Ts[c + u][d];
        uint4* dst = (uint4*)(vt + ((size_t)bh * DK + d) * 640 + n0 + c);
        dst[0] = *(uint4*)&tmp[0];
        dst[1] = *(uint4*)&tmp[8];
    }
}

// ---------- flash attention: 512 threads, QBLK=128, 8 waves of 16-row strips ----------
__global__ __launch_bounds__(512, 4) void k_attn2(const unsigned short* __restrict__ qh,
                                                  const unsigned short* __restrict__ kh,
                                                  const unsigned short* __restrict__ vt,
                                                  const float* __restrict__ pen,
                                                  unsigned short* __restrict__ O) {
    const int NWG = 5 * NH * B_;               // 960
    int flat = blockIdx.x + 5 * (blockIdx.y + NH * blockIdx.z);
    int id = (flat & 7) * (NWG >> 3) + (flat >> 3);
    int it = id % 5; int t2 = id / 5;
    int h = t2 % NH;  int b = t2 / NH;
    int bh = b * NH + h;
    int i0 = it * 128;

    __shared__ __align__(16) unsigned short Qs[128][72];
    __shared__ __align__(16) unsigned short Ks[64][72];
    __shared__ __align__(16) unsigned short Vs[64][72];
    __shared__ __align__(16) unsigned short Ps[128][72];
    int tid = threadIdx.x;
    int lane = tid & 63, w = tid >> 6;          // 8 waves

    {
        int r = tid >> 2, c = (tid & 3) * 16;
        int gi = i0 + r; if (gi > 576) gi = 576;
        const uint4* src = (const uint4*)(qh + ((size_t)bh * SEQ + gi) * DK + c);
        uint4 a = src[0], bv = src[1];
        *(uint4*)&Qs[r][c] = a; *(uint4*)&Qs[r][c + 8] = bv;
    }
    __syncthreads();
    short8 qfrag[2];
    #pragma unroll
    for (int s = 0; s < 2; s++)
        qfrag[s] = *(const short8*)&Qs[w * 16 + (lane & 15)][s * 32 + (lane >> 4) * 8];

    f32x4 o_acc[4];
    #pragma unroll
    for (int i = 0; i < 4; i++) o_acc[i] = (f32x4){0.f, 0.f, 0.f, 0.f};
    float m_run[4], l_run[4];
    #pragma unroll
    for (int r = 0; r < 4; r++) { m_run[r] = -1e30f; l_run[r] = 0.f; }

    const float* penb = pen + (size_t)b * P_ * P_;
    int colbase = lane & 15;
    int rloc = (lane >> 4) * 4;

    const float* prow[4]; bool iok[4];
    #pragma unroll
    for (int rg = 0; rg < 4; rg++) {
        int i = i0 + w * 16 + rloc + rg;
        int ii = i < 1 ? 1 : (i > 576 ? 576 : i);
        prow[rg] = penb + (size_t)(ii - 1) * P_;
        iok[rg] = (i >= 1 && i <= 576);
    }

    for (int kt = 0; kt < 10; kt++) {
        int j0 = kt * 64;
        {
            int r = tid >> 3, c = (tid & 7) * 8;
            int gj = j0 + r; if (gj > 576) gj = 576;
            *(uint4*)&Ks[r][c] = *(const uint4*)(kh + ((size_t)bh * SEQ + gj) * DK + c);
            *(uint4*)&Vs[r][c] = *(const uint4*)(vt + ((size_t)bh * DK + r) * 640 + j0 + c);
        }
        __syncthreads();

        float pf[4][4];
        #pragma unroll
        for (int rg = 0; rg < 4; rg++) {
            #pragma unroll
            for (int nt = 0; nt < 4; nt++) {
                int j = j0 + nt * 16 + colbase;
                int jj = j < 1 ? 1 : (j > 576 ? 576 : j);
                float pv = prow[rg][jj - 1];
                pf[rg][nt] = (iok[rg] && j >= 1 && j <= 576) ? pv : 0.f;
            }
        }

        f32x4 sfrag[4];
        __builtin_amdgcn_s_setprio(1);
        #pragma unroll
        for (int nt = 0; nt < 4; nt++) {
            f32x4 acc = (f32x4){0.f, 0.f, 0.f, 0.f};
            #pragma unroll
            for (int s = 0; s < 2; s++) {
                short8 bfrag = *(const short8*)&Ks[nt * 16 + colbase][s * 32 + (lane >> 4) * 8];
                acc = __builtin_amdgcn_mfma_f32_16x16x32_bf16(qfrag[s], bfrag, acc, 0, 0, 0);
            }
            sfrag[nt] = acc;
        }
        __builtin_amdgcn_s_setprio(0);

        #pragma unroll
        for (int nt = 0; nt < 4; nt++) {
            int j = j0 + nt * 16 + colbase;
            #pragma unroll
            for (int rg = 0; rg < 4; rg++) {
                float sv = sfrag[nt][rg] - pf[rg][nt];
                if (j > 576) sv = -1e30f;
                sfrag[nt][rg] = sv;
            }
        }
        float alpha[4];
        #pragma unroll
        for (int rg = 0; rg < 4; rg++) {
            float t = fmaxf(fmaxf(sfrag[0][rg], sfrag[1][rg]),
                            fmaxf(sfrag[2][rg], sfrag[3][rg]));
            #pragma unroll
            for (int off = 1; off < 16; off <<= 1) t = fmaxf(t, __shfl_xor(t, off, 64));
            float mn = fmaxf(m_run[rg], t);
            alpha[rg] = __expf(m_run[rg] - mn);
            m_run[rg] = mn;
        }
        float rsum[4] = {0.f, 0.f, 0.f, 0.f};
        #pragma unroll
        for (int nt = 0; nt < 4; nt++) {
            #pragma unroll
            for (int rg = 0; rg < 4; rg++) {
                float p = __expf(sfrag[nt][rg] - m_run[rg]);
                rsum[rg] += p;
                Ps[w * 16 + rloc + rg][nt * 16 + colbase] = f2bu(p);
            }
        }
        #pragma unroll
        for (int rg = 0; rg < 4; rg++) {
            float t = rsum[rg];
            #pragma unroll
            for (int off = 1; off < 16; off <<= 1) t += __shfl_xor(t, off, 64);
            l_run[rg] = l_run[rg] * alpha[rg] + t;
        }
        #pragma unroll
        for (int nt = 0; nt < 4; nt++)
            #pragma unroll
            for (int rg = 0; rg < 4; rg++) o_acc[nt][rg] *= alpha[rg];

        __builtin_amdgcn_s_setprio(1);
        #pragma unroll
        for (int s = 0; s < 2; s++) {
            short8 afrag = *(const short8*)&Ps[w * 16 + (lane & 15)][s * 32 + (lane >> 4) * 8];
            #pragma unroll
            for (int nt = 0; nt < 4; nt++) {
                short8 bfrag = *(const short8*)&Vs[nt * 16 + colbase][s * 32 + (lane >> 4) * 8];
                o_acc[nt] = __builtin_amdgcn_mfma_f32_16x16x32_bf16(afrag, bfrag, o_acc[nt], 0, 0, 0);
            }
        }
        __builtin_amdgcn_s_setprio(0);
        __syncthreads();
    }
    #pragma unroll
    for (int rg = 0; rg < 4; rg++) {
        int i = i0 + w * 16 + rloc + rg;
        if (i < SEQ) {
            float linv = 1.0f / l_run[rg];
            #pragma unroll
            for (int nt = 0; nt < 4; nt++) {
                int d = nt * 16 + colbase;
                O[(((size_t)(b * SEQ + i)) * NH + h) * DK + d] = f2bu(o_acc[nt][rg] * linv);
            }
        }
    }
}

// ---------- out projection via MFMA + gload_lds + T2 granule swizzle ----------
__global__ __launch_bounds__(256) void k_fc_mfma(const unsigned short* __restrict__ Obf,
                                                 const unsigned short* __restrict__ wtfc,
                                                 const void* __restrict__ qin,
                                                 const void* __restrict__ gamma,
                                                 float* __restrict__ fcout) {
    bool bf = bf_flag(gamma);
    int p = xcd_chunk(blockIdx.x, 73 * 6);
    int m0 = (p / 6) * 128, n0 = (p % 6) * 128;
    __shared__ __align__(16) unsigned short As[128][64];
    __shared__ __align__(16) unsigned short Bs2[128][64];
    int tid = threadIdx.x;
    int lane = tid & 63, w = tid >> 6;
    int wr = w >> 1, wc = w & 1;
    int r3 = lane & 7;

    f32x4 acc[4][4];
    #pragma unroll
    for (int r = 0; r < 4; r++)
        #pragma unroll
        for (int c = 0; c < 4; c++) acc[r][c] = (f32x4){0.f, 0.f, 0.f, 0.f};

    const unsigned short *aS[4], *bS[4]; void *aD[4], *bD[4];
    #pragma unroll
    for (int s = 0; s < 4; s++) {
        int S = w * 4 + s;
        int rl = S * 8 + (lane >> 3);
        int ra = m0 + rl; if (ra >= MROWS) ra = MROWS - 1;
        int gsw = (lane & 7) ^ (lane >> 3);
        aS[s] = Obf + (size_t)ra * DM + (gsw << 3);
        bS[s] = wtfc + (size_t)(n0 + rl) * DM + (gsw << 3);
        aD[s] = &As[S * 8][0]; bD[s] = &Bs2[S * 8][0];
    }

    for (int kc = 0; kc < DM; kc += 64) {
        #pragma unroll
        for (int s = 0; s < 4; s++) { gload16(aS[s] + kc, aD[s]); gload16(bS[s] + kc, bD[s]); }
        __syncthreads();
        #pragma unroll
        for (int s = 0; s < 2; s++) {
            int g16 = (s * 4 + (lane >> 4)) ^ r3;
            short8 af[4], bfr[4];
            #pragma unroll
            for (int r = 0; r < 4; r++)
                af[r] = *(const short8*)((const char*)&As[wr * 64 + r * 16 + (lane & 15)][0] + (g16 << 4));
            #pragma unroll
            for (int c = 0; c < 4; c++)
                bfr[c] = *(const short8*)((const char*)&Bs2[wc * 64 + c * 16 + (lane & 15)][0] + (g16 << 4));
            #pragma unroll
            for (int r = 0; r < 4; r++)
                #pragma unroll
                for (int c = 0; c < 4; c++)
                    acc[r][c] = __builtin_amdgcn_mfma_f32_16x16x32_bf16(af[r], bfr[c], acc[r][c], 0, 0, 0);
        }
        __syncthreads();
    }
    int rbase = (lane >> 4) * 4, cbase = lane & 15;
    #pragma unroll
    for (int r = 0; r < 4; r++) {
        #pragma unroll
        for (int jj = 0; jj < 4; jj++) {
            int gm = m0 + wr * 64 + r * 16 + rbase + jj;
            if (gm < MROWS) {
                #pragma unroll
                for (int c = 0; c < 4; c++) {
                    int gc = n0 + wc * 64 + c * 16 + cbase;
                    fcout[(size_t)gm * DM + gc] = acc[r][c][jj] + ldf(qin, (size_t)gm * DM + gc, bf);
                }
            }
        }
    }
}

// ---------- layernorm (dtype-adaptive output) ----------
__global__ __launch_bounds__(256) void k_ln(const float* __restrict__ x,
                                            const void* __restrict__ gamma,
                                            const void* __restrict__ beta,
                                            void* __restrict__ out) {
    bool bf = bf_flag(gamma);
    int row = blockIdx.x;
    const float* xr = x + (size_t)row * DM;
    int tid = threadIdx.x;
    float v[3];
    float ssum = 0.f;
    #pragma unroll
    for (int u = 0; u < 3; u++) { v[u] = xr[tid + u * 256]; ssum += v[u]; }
    __shared__ float red[4];
    __shared__ float mu_s, var_s;
    float t = ssum;
    for (int off = 32; off > 0; off >>= 1) t += __shfl_down(t, off, 64);
    int lane = tid & 63, w = tid >> 6;
    if (lane == 0) red[w] = t;
    __syncthreads();
    if (tid == 0) mu_s = (red[0] + red[1] + red[2] + red[3]) * (1.0f / DM);
    __syncthreads();
    float mu = mu_s;
    float vs = 0.f;
    #pragma unroll
    for (int u = 0; u < 3; u++) { float d = v[u] - mu; vs += d * d; }
    t = vs;
    for (int off = 32; off > 0; off >>= 1) t += __shfl_down(t, off, 64);
    if (lane == 0) red[w] = t;
    __syncthreads();
    if (tid == 0) var_s = (red[0] + red[1] + red[2] + red[3]) * (1.0f / DM);
    __syncthreads();
    float rstd = rsqrtf(var_s + LNEPS);
    #pragma unroll
    for (int u = 0; u < 3; u++) {
        int c = tid + u * 256;
        float val = (v[u] - mu) * rstd * ldf(gamma, c, bf) + ldf(beta, c, bf);
        size_t idx = (size_t)row * DM + c;
        if (bf) ((__hip_bfloat16*)out)[idx] = __float2bfloat16(val);
        else    ((float*)out)[idx] = val;
    }
}

extern "C" void kernel_launch(void* const* d_in, const int* in_sizes, int n_in,
                              void* d_out, int out_size, void* d_ws, size_t ws_size,
                              hipStream_t stream) {
    const void* q   = d_in[0];
    const void* k   = d_in[1];
    const void* v   = d_in[2];
    const void* pos = d_in[3];
    const void* pe  = d_in[4];
    const void* wq  = d_in[5];
    const void* wk  = d_in[6];
    const void* wv  = d_in[7];
    const void* wfc = d_in[8];
    const void* gam = d_in[9];
    const void* bet = d_in[10];
    char* wsb = (char*)d_ws;
    float*          pen = (float*)(wsb + PEN_B);
    unsigned short* qh  = (unsigned short*)(wsb + QH_B);
    unsigned short* kh  = (unsigned short*)(wsb + KH_B);
    unsigned short* vh  = (unsigned short*)(wsb + VH_B);
    unsigned short* vt  = (unsigned short*)(wsb + VT_B);
    unsigned short* Obf = (unsigned short*)(wsb + OBF_B);
    unsigned short* wt  = (unsigned short*)(wsb + WT_B);
    float*          rn  = (float*)(wsb + RN_B);
    float*          fc  = (float*)(wsb + FC_B);

    k_wt<<<dim3(12, 12, 4), 256, 0, stream>>>(wq, wk, wv, wfc, gam, wt);
    k_rownorm<<<B_ * P_, 256, 0, stream>>>(pe, gam, rn);
    k_penalty_mfma<<<dim3(9 * 9 * B_), 256, 0, stream>>>(pe, pos, gam, rn, pen);
    k_proj_mfma<<<dim3(73 * 6 * 3), 256, 0, stream>>>(q, k, v, wt, gam, qh, kh, vh);
    k_vt<<<dim3(10, 192), 256, 0, stream>>>(vh, vt);
    k_attn2<<<dim3(5, NH, B_), 512, 0, stream>>>(qh, kh, vt, pen, Obf);
    k_fc_mfma<<<dim3(73 * 6), 256, 0, stream>>>(Obf, wt + (size_t)3 * DM * DM, q, gam, fc);
    k_ln<<<MROWS, 256, 0, stream>>>(fc, gam, bet, d_out);
}